// Round 7
// baseline (136.641 us; speedup 1.0000x reference)
//
#include <hip/hip_runtime.h>

typedef float f32x4 __attribute__((ext_vector_type(4)));
typedef __bf16 bf16x8 __attribute__((ext_vector_type(8)));
typedef unsigned short u16x8 __attribute__((ext_vector_type(8)));

static constexpr int B_ = 8, Cin = 128, Cout = 128, K2 = 9;
static constexpr int HW  = 64 * 64;      // 4096
static constexpr int CHW = Cin * HW;     // 524288
static constexpr int KC  = Cin * K2;     // 1152
static constexpr int SLD = 136;          // LDS row stride (u16), 272B

static __device__ __forceinline__ unsigned short f2bf(float f) {
  unsigned int u = __builtin_bit_cast(unsigned int, f);
  u = u + 0x7fffu + ((u >> 16) & 1u);
  return (unsigned short)(u >> 16);
}
static __device__ __forceinline__ float b2f(unsigned short u) {
  return __builtin_bit_cast(float, ((unsigned int)u) << 16);
}

// ---------------- prep: lane-contiguous MFMA A-operand layouts ----------------
// wsW2:  [w(8)][k(9)][ks(4)][lane(64)][j(8)]  <- deform W, oc=w*16+(lane&15), c=ks*32+(lane>>4)*8+j
// wOffB2:[r(9)][ks(4)][m(2)][lane(64)][j(8)]  <- offset W (oc pad 18->32)
__global__ __launch_bounds__(256) void prep_kernel(
    const float* __restrict__ dw, const float* __restrict__ ow,
    unsigned short* __restrict__ wsW2, unsigned short* __restrict__ wOffB2) {
  int i = blockIdx.x * 256 + threadIdx.x;
  if (i < 8 * 9 * 4 * 512) {
    int j = i & 7, lane = (i >> 3) & 63, ks = (i >> 9) & 3, t2 = i >> 11;
    int k = t2 % 9, w = t2 / 9;
    int oc = w * 16 + (lane & 15);
    int c = ks * 32 + (lane >> 4) * 8 + j;
    wsW2[i] = f2bf(dw[(oc * Cin + c) * K2 + k]);
  }
  if (i < 9 * 4 * 2 * 512) {
    int j = i & 7, lane = (i >> 3) & 63, m = (i >> 9) & 1, t3 = i >> 10;
    int ks = t3 & 3, r = t3 >> 2;
    int oc = m * 16 + (lane & 15);
    int c = ks * 32 + (lane >> 4) * 8 + j;
    wOffB2[i] = (oc < 18) ? f2bf(ow[(oc * Cin + c) * K2 + r]) : (unsigned short)0;
  }
}

// ---------------- transpose: x NCHW f32 -> xt NHWC bf16 ----------------
__global__ __launch_bounds__(256) void trans_kernel(
    const float* __restrict__ x, unsigned short* __restrict__ xt) {
  int bid = blockIdx.x;
  int swz = (bid & 7) * 64 + (bid >> 3);
  int b = swz >> 6, y = swz & 63;
  int t = threadIdx.x;
  int lane = t & 63, cq = t >> 6;

  __shared__ unsigned short L[64 * SLD];
  const float* xb = x + b * CHW + y * 64;
#pragma unroll
  for (int i = 0; i < 32; ++i) {
    int c = i * 4 + cq;
    L[lane * SLD + c] = f2bf(xb[c * HW + lane]);
  }
  __syncthreads();
  int p = t >> 2, q = t & 3;
  unsigned short* op = xt + (size_t)b * HW * 128 + y * 64 * 128 + p * 128 + q * 32;
#pragma unroll
  for (int s = 0; s < 4; ++s)
    *(u16x8*)(op + s * 8) = *(const u16x8*)&L[p * SLD + q * 32 + s * 8];
}

// ---------------- offset conv (MFMA) + bilinear record precompute ----------------
__global__ __launch_bounds__(256) void offs_kernel(
    const unsigned short* __restrict__ xt, const unsigned short* __restrict__ wOffB2,
    const float* __restrict__ ob, float4* __restrict__ w4out,
    unsigned int* __restrict__ idxout) {
  int bid = blockIdx.x;
  int swz = (bid & 7) * 64 + (bid >> 3);
  int b = swz >> 6, ho = swz & 63;
  int t = threadIdx.x;
  int pos = t & 63, cg = t >> 6;                   // staging: 4 cg x 32 ch
  int lane = t & 63, w = t >> 6;
  int col = lane & 15, g = lane >> 4;

  __shared__ unsigned short So[2][64 * SLD];
  __shared__ float T[64 * 20];

  f32x4 acc[2];
  acc[0] = (f32x4){0.f, 0.f, 0.f, 0.f};
  acc[1] = (f32x4){0.f, 0.f, 0.f, 0.f};

  const unsigned short* xtb = xt + (size_t)b * HW * 128;

  auto stage = [&](int r, int buf) {
    int ky = r / 3, kx = r % 3;
    int yv = ho + ky - 1, xc = pos + kx - 1;
    bool ok = ((unsigned)yv < 64u) && ((unsigned)xc < 64u);
    int yc = min(max(yv, 0), 63), xcc = min(max(xc, 0), 63);
    const unsigned short* q = xtb + (yc * 64 + xcc) * 128 + cg * 32;
#pragma unroll
    for (int i = 0; i < 4; ++i) {
      u16x8 sm = *(const u16x8*)(q + i * 8);
      if (!ok) sm = (u16x8){0, 0, 0, 0, 0, 0, 0, 0};
      *(u16x8*)&So[buf][pos * SLD + cg * 32 + i * 8] = sm;
    }
  };

  stage(0, 0);
  __syncthreads();

  for (int r = 0; r < 9; ++r) {
    int cur = r & 1;
    if (r < 8) stage(r + 1, cur ^ 1);
#pragma unroll
    for (int ks = 0; ks < 4; ++ks) {
      bf16x8 bfr = *(const bf16x8*)&So[cur][(w * 16 + col) * SLD + ks * 32 + g * 8];
      u16x8 af0 = *(const u16x8*)(wOffB2 + ((r * 4 + ks) * 2 + 0) * 512 + lane * 8);
      u16x8 af1 = *(const u16x8*)(wOffB2 + ((r * 4 + ks) * 2 + 1) * 512 + lane * 8);
      acc[0] = __builtin_amdgcn_mfma_f32_16x16x32_bf16(
          __builtin_bit_cast(bf16x8, af0), bfr, acc[0], 0, 0, 0);
      acc[1] = __builtin_amdgcn_mfma_f32_16x16x32_bf16(
          __builtin_bit_cast(bf16x8, af1), bfr, acc[1], 0, 0, 0);
    }
    __syncthreads();
  }

  // transpose D -> T[pos][oc] with bias
#pragma unroll
  for (int m = 0; m < 2; ++m)
#pragma unroll
    for (int rg = 0; rg < 4; ++rg) {
      int row = m * 16 + g * 4 + rg;
      if (row < 18) T[(w * 16 + col) * 20 + row] = acc[m][rg] + ob[row];
    }
  __syncthreads();

  if (t < 64) {
#pragma unroll
    for (int k = 0; k < 9; ++k) {
      float dy = T[t * 20 + 2 * k], dx = T[t * 20 + 2 * k + 1];
      float py = (float)(ho - 1 + k / 3) + dy;
      float px = (float)(t - 1 + k % 3) + dx;
      float y0f = floorf(py), x0f = floorf(px);
      float wy1 = py - y0f, wy0 = 1.f - wy1;
      float wx1 = px - x0f, wx0 = 1.f - wx1;
      int y0 = (int)y0f, x0 = (int)x0f;
      bool vy0 = (unsigned)y0 < 64u, vy1 = (unsigned)(y0 + 1) < 64u;
      bool vx0 = (unsigned)x0 < 64u, vx1 = (unsigned)(x0 + 1) < 64u;
      float w00 = (vy0 && vx0) ? wy0 * wx0 : 0.f;
      float w01 = (vy0 && vx1) ? wy0 * wx1 : 0.f;
      float w10 = (vy1 && vx0) ? wy1 * wx0 : 0.f;
      float w11 = (vy1 && vx1) ? wy1 * wx1 : 0.f;
      int y0c = min(max(y0, 0), 63), y1c = min(max(y0 + 1, 0), 63);
      int xb2 = min(max(x0, 0), 62);
      unsigned off0 = (unsigned)(y0c * 64 + xb2);
      unsigned off1 = (unsigned)(y1c * 64 + xb2);
      unsigned pkw = off0 | (off1 << 12);
      if (x0 == 63) pkw |= (1u << 24);   // left value is loaded col+1
      if (x0 == -1) pkw |= (1u << 25);   // right value is loaded col
      int rec = (b * 9 + k) * HW + ho * 64 + t;
      w4out[rec] = make_float4(w00, w01, w10, w11);
      idxout[rec] = pkw;
    }
  }
}

// ---------------- fused deformable-im2col + MFMA GEMM + BN + SiLU ----------------
// 512 thr = 8 waves; wave w owns oc [w*16,w*16+16). Gather from NHWC bf16 xt:
// per thread per k: 8 x 16B vector loads (4 corners x 16ch), vs 64 scalar before.
__global__ __launch_bounds__(512, 4) void gemm_kernel(
    const unsigned short* __restrict__ xt, const unsigned short* __restrict__ wsW2,
    const float4* __restrict__ w4in, const unsigned int* __restrict__ idxin,
    const float* __restrict__ dbias, const float* __restrict__ gamma,
    const float* __restrict__ beta, const float* __restrict__ mean,
    const float* __restrict__ var, float* __restrict__ out) {
  int bid = blockIdx.x;
  int swz = (bid & 7) * 64 + (bid >> 3);           // XCD i <- batch i
  int b = swz >> 6, ho = swz & 63;
  int t = threadIdx.x;
  int pos = t & 63, cg = t >> 6;                   // gather: 8 cg x 16 ch
  int lane = t & 63, w = t >> 6;
  int col = lane & 15, g = lane >> 4;

  __shared__ unsigned short S[2][64 * SLD];

  f32x4 acc[4];
#pragma unroll
  for (int j = 0; j < 4; ++j) acc[j] = (f32x4){0.f, 0.f, 0.f, 0.f};

  const unsigned short* xtb = xt + (size_t)b * HW * 128 + cg * 16;
  const unsigned short* wA = wsW2 + w * (9 * 4 * 512) + lane * 8;
  const float4* w4p = w4in + b * 9 * HW + ho * 64 + pos;
  const unsigned int* idxp = idxin + b * 9 * HW + ho * 64 + pos;

  auto combine = [&](const u16x8& gl, const u16x8& gr,
                     const u16x8& hl, const u16x8& hr,
                     bool s0, bool s1, const float4& w4) -> u16x8 {
    u16x8 sm;
#pragma unroll
    for (int j = 0; j < 8; ++j) {
      float v00 = b2f(gl[j]), v01 = b2f(gr[j]);
      float v10 = b2f(hl[j]), v11 = b2f(hr[j]);
      float a0 = s0 ? v01 : v00, a1 = s1 ? v00 : v01;
      float a2 = s0 ? v11 : v10, a3 = s1 ? v10 : v11;
      sm[j] = f2bf(w4.x * a0 + w4.y * a1 + w4.z * a2 + w4.w * a3);
    }
    return sm;
  };

  // prologue: gather k=0, write S[0]
  {
    float4 gw4 = w4p[0];
    unsigned gpk = idxp[0];
    int o0 = gpk & 4095, o1 = (gpk >> 12) & 4095;
    bool s0 = (gpk >> 24) & 1, s1 = (gpk >> 25) & 1;
#pragma unroll
    for (int h = 0; h < 2; ++h) {
      u16x8 c00 = *(const u16x8*)(xtb + o0 * 128 + h * 8);
      u16x8 c01 = *(const u16x8*)(xtb + o0 * 128 + 128 + h * 8);
      u16x8 c10 = *(const u16x8*)(xtb + o1 * 128 + h * 8);
      u16x8 c11 = *(const u16x8*)(xtb + o1 * 128 + 128 + h * 8);
      u16x8 sm = combine(c00, c01, c10, c11, s0, s1, gw4);
      *(u16x8*)&S[0][pos * SLD + cg * 16 + h * 8] = sm;
    }
  }
  float4 rw4n = w4p[HW];                           // rec[1]
  unsigned rpkn = idxp[HW];
  __syncthreads();

  for (int k = 0; k < 9; ++k) {
    int cur = k & 1;
    bool hasg = (k < 8);
    float4 gw4 = rw4n;
    bool s0 = false, s1 = false;
    u16x8 c00a, c01a, c10a, c11a, c00b, c01b, c10b, c11b;
    if (hasg) {                                    // issue gathers for k+1
      unsigned gpk = rpkn;
      int o0 = gpk & 4095, o1 = (gpk >> 12) & 4095;
      s0 = (gpk >> 24) & 1; s1 = (gpk >> 25) & 1;
      const unsigned short* r00 = xtb + o0 * 128;
      const unsigned short* r10 = xtb + o1 * 128;
      c00a = *(const u16x8*)(r00);       c00b = *(const u16x8*)(r00 + 8);
      c01a = *(const u16x8*)(r00 + 128); c01b = *(const u16x8*)(r00 + 136);
      c10a = *(const u16x8*)(r10);       c10b = *(const u16x8*)(r10 + 8);
      c11a = *(const u16x8*)(r10 + 128); c11b = *(const u16x8*)(r10 + 136);
      if (k < 7) { rw4n = w4p[(k + 2) * HW]; rpkn = idxp[(k + 2) * HW]; }
    }
    // A-frags (lane-contiguous, coalesced)
    u16x8 af[4];
#pragma unroll
    for (int ks = 0; ks < 4; ++ks)
      af[ks] = *(const u16x8*)(wA + (k * 4 + ks) * 512);
#pragma unroll
    for (int pt = 0; pt < 2; ++pt)                 // MFMA pt 0,1
#pragma unroll
      for (int ks = 0; ks < 4; ++ks) {
        bf16x8 bfr = *(const bf16x8*)&S[cur][(pt * 16 + col) * SLD + ks * 32 + g * 8];
        acc[pt] = __builtin_amdgcn_mfma_f32_16x16x32_bf16(
            __builtin_bit_cast(bf16x8, af[ks]), bfr, acc[pt], 0, 0, 0);
      }
    if (hasg) {                                    // combine + write S[cur^1]
      u16x8 sa = combine(c00a, c01a, c10a, c11a, s0, s1, gw4);
      *(u16x8*)&S[cur ^ 1][pos * SLD + cg * 16] = sa;
      u16x8 sb = combine(c00b, c01b, c10b, c11b, s0, s1, gw4);
      *(u16x8*)&S[cur ^ 1][pos * SLD + cg * 16 + 8] = sb;
    }
#pragma unroll
    for (int pt = 2; pt < 4; ++pt)                 // MFMA pt 2,3
#pragma unroll
      for (int ks = 0; ks < 4; ++ks) {
        bf16x8 bfr = *(const bf16x8*)&S[cur][(pt * 16 + col) * SLD + ks * 32 + g * 8];
        acc[pt] = __builtin_amdgcn_mfma_f32_16x16x32_bf16(
            __builtin_bit_cast(bf16x8, af[ks]), bfr, acc[pt], 0, 0, 0);
      }
    __syncthreads();
  }

  // epilogue: bias + BN + SiLU, write NCHW
  float* op = out + b * (Cout * HW) + ho * 64;
  int ocb = w * 16 + g * 4;
#pragma unroll
  for (int r = 0; r < 4; ++r) {
    int oc = ocb + r;
    float sc = gamma[oc] * rsqrtf(var[oc] + 1e-5f);
    float bs = beta[oc] - mean[oc] * sc;
    float db = dbias[oc];
#pragma unroll
    for (int pt = 0; pt < 4; ++pt) {
      float v = (acc[pt][r] + db) * sc + bs;
      op[oc * HW + pt * 16 + col] = v / (1.f + __expf(-v));
    }
  }
}

extern "C" void kernel_launch(void* const* d_in, const int* in_sizes, int n_in,
                              void* d_out, int out_size, void* d_ws, size_t ws_size,
                              hipStream_t stream) {
  const float* x     = (const float*)d_in[0];
  const float* ow    = (const float*)d_in[1];
  const float* ob    = (const float*)d_in[2];
  const float* dw    = (const float*)d_in[3];
  const float* db    = (const float*)d_in[4];
  const float* gamma = (const float*)d_in[5];
  const float* beta  = (const float*)d_in[6];
  const float* mean  = (const float*)d_in[7];
  const float* var   = (const float*)d_in[8];

  char* wsc = (char*)d_ws;
  unsigned short* wsW2   = (unsigned short*)wsc;               // 294912 B
  unsigned short* wOffB2 = (unsigned short*)(wsc + 294912);    // 73728 B
  unsigned short* xt     = (unsigned short*)(wsc + 368640);    // 8388608 B
  float4* w4rec          = (float4*)(wsc + 8757248);           // 4718592 B
  unsigned int* idxrec   = (unsigned int*)(wsc + 13475840);    // 1179648 B

  prep_kernel<<<576, 256, 0, stream>>>(dw, ow, wsW2, wOffB2);
  trans_kernel<<<512, 256, 0, stream>>>(x, xt);
  offs_kernel<<<512, 256, 0, stream>>>(xt, wOffB2, ob, w4rec, idxrec);
  gemm_kernel<<<512, 512, 0, stream>>>(xt, wsW2, w4rec, idxrec, db, gamma, beta,
                                       mean, var, (float*)d_out);
}

// Round 8
// 66.335 us; speedup vs baseline: 2.0599x; 2.0599x over previous
//
#include <hip/hip_runtime.h>

typedef float f32x4 __attribute__((ext_vector_type(4)));
typedef __bf16 bf16x8 __attribute__((ext_vector_type(8)));
typedef unsigned short u16x8 __attribute__((ext_vector_type(8)));

static constexpr int B_ = 8, Cin = 128, Cout = 128, K2 = 9;
static constexpr int HW  = 64 * 64;      // 4096
static constexpr int CHW = Cin * HW;     // 524288
static constexpr int KC  = Cin * K2;     // 1152
static constexpr int SLD = 136;          // LDS row stride (u16), 272B

static __device__ __forceinline__ unsigned short f2bf(float f) {
  unsigned int u = __builtin_bit_cast(unsigned int, f);
  u = u + 0x7fffu + ((u >> 16) & 1u);
  return (unsigned short)(u >> 16);
}
static __device__ __forceinline__ float b2f_lo(unsigned int u) {
  return __builtin_bit_cast(float, u << 16);
}
static __device__ __forceinline__ float b2f_hi(unsigned int u) {
  return __builtin_bit_cast(float, u & 0xffff0000u);
}

// ---------------- prep: lane-contiguous MFMA A-operand layouts ----------------
// wsW2:  [w(8)][k(9)][ks(4)][lane(64)][j(8)]  <- deform W
// wOffB2:[r(9)][ks(4)][m(2)][lane(64)][j(8)]  <- offset W (oc pad 18->32)
__global__ __launch_bounds__(256) void prep_kernel(
    const float* __restrict__ dw, const float* __restrict__ ow,
    unsigned short* __restrict__ wsW2, unsigned short* __restrict__ wOffB2) {
  int i = blockIdx.x * 256 + threadIdx.x;
  if (i < 8 * 9 * 4 * 512) {
    int j = i & 7, lane = (i >> 3) & 63, ks = (i >> 9) & 3, t2 = i >> 11;
    int k = t2 % 9, w = t2 / 9;
    int oc = w * 16 + (lane & 15);
    int c = ks * 32 + (lane >> 4) * 8 + j;
    wsW2[i] = f2bf(dw[(oc * Cin + c) * K2 + k]);
  }
  if (i < 9 * 4 * 2 * 512) {
    int j = i & 7, lane = (i >> 3) & 63, m = (i >> 9) & 1, t3 = i >> 10;
    int ks = t3 & 3, r = t3 >> 2;
    int oc = m * 16 + (lane & 15);
    int c = ks * 32 + (lane >> 4) * 8 + j;
    wOffB2[i] = (oc < 18) ? f2bf(ow[(oc * Cin + c) * K2 + r]) : (unsigned short)0;
  }
}

// ---------------- transpose: x NCHW f32 -> xt NHWC bf16 ----------------
__global__ __launch_bounds__(256) void trans_kernel(
    const float* __restrict__ x, unsigned short* __restrict__ xt) {
  int bid = blockIdx.x;
  int swz = (bid & 7) * 64 + (bid >> 3);
  int b = swz >> 6, y = swz & 63;
  int t = threadIdx.x;
  int lane = t & 63, cq = t >> 6;

  __shared__ unsigned short L[64 * SLD];
  const float* xb = x + b * CHW + y * 64;
#pragma unroll
  for (int i = 0; i < 32; ++i) {
    int c = i * 4 + cq;
    L[lane * SLD + c] = f2bf(xb[c * HW + lane]);
  }
  __syncthreads();
  int p = t >> 2, q = t & 3;
  unsigned short* op = xt + (size_t)b * HW * 128 + y * 64 * 128 + p * 128 + q * 32;
#pragma unroll
  for (int s = 0; s < 4; ++s)
    *(u16x8*)(op + s * 8) = *(const u16x8*)&L[p * SLD + q * 32 + s * 8];
}

// ---------------- offset conv (MFMA) + bilinear record precompute ----------------
__global__ __launch_bounds__(256) void offs_kernel(
    const unsigned short* __restrict__ xt, const unsigned short* __restrict__ wOffB2,
    const float* __restrict__ ob, float4* __restrict__ w4out,
    unsigned int* __restrict__ idxout) {
  int bid = blockIdx.x;
  int swz = (bid & 7) * 64 + (bid >> 3);
  int b = swz >> 6, ho = swz & 63;
  int t = threadIdx.x;
  int pos = t & 63, cg = t >> 6;
  int lane = t & 63, w = t >> 6;
  int col = lane & 15, g = lane >> 4;

  __shared__ unsigned short So[2][64 * SLD];
  __shared__ float T[64 * 20];

  f32x4 acc[2];
  acc[0] = (f32x4){0.f, 0.f, 0.f, 0.f};
  acc[1] = (f32x4){0.f, 0.f, 0.f, 0.f};

  const unsigned short* xtb = xt + (size_t)b * HW * 128;

  auto stage = [&](int r, int buf) {
    int ky = r / 3, kx = r % 3;
    int yv = ho + ky - 1, xc = pos + kx - 1;
    bool ok = ((unsigned)yv < 64u) && ((unsigned)xc < 64u);
    int yc = min(max(yv, 0), 63), xcc = min(max(xc, 0), 63);
    const unsigned short* q = xtb + (yc * 64 + xcc) * 128 + cg * 32;
#pragma unroll
    for (int i = 0; i < 4; ++i) {
      u16x8 sm = *(const u16x8*)(q + i * 8);
      if (!ok) sm = (u16x8){0, 0, 0, 0, 0, 0, 0, 0};
      *(u16x8*)&So[buf][pos * SLD + cg * 32 + i * 8] = sm;
    }
  };

  stage(0, 0);
  __syncthreads();

  for (int r = 0; r < 9; ++r) {
    int cur = r & 1;
    if (r < 8) stage(r + 1, cur ^ 1);
#pragma unroll
    for (int ks = 0; ks < 4; ++ks) {
      bf16x8 bfr = *(const bf16x8*)&So[cur][(w * 16 + col) * SLD + ks * 32 + g * 8];
      u16x8 af0 = *(const u16x8*)(wOffB2 + ((r * 4 + ks) * 2 + 0) * 512 + lane * 8);
      u16x8 af1 = *(const u16x8*)(wOffB2 + ((r * 4 + ks) * 2 + 1) * 512 + lane * 8);
      acc[0] = __builtin_amdgcn_mfma_f32_16x16x32_bf16(
          __builtin_bit_cast(bf16x8, af0), bfr, acc[0], 0, 0, 0);
      acc[1] = __builtin_amdgcn_mfma_f32_16x16x32_bf16(
          __builtin_bit_cast(bf16x8, af1), bfr, acc[1], 0, 0, 0);
    }
    __syncthreads();
  }

#pragma unroll
  for (int m = 0; m < 2; ++m)
#pragma unroll
    for (int rg = 0; rg < 4; ++rg) {
      int row = m * 16 + g * 4 + rg;
      if (row < 18) T[(w * 16 + col) * 20 + row] = acc[m][rg] + ob[row];
    }
  __syncthreads();

  if (t < 64) {
#pragma unroll
    for (int k = 0; k < 9; ++k) {
      float dy = T[t * 20 + 2 * k], dx = T[t * 20 + 2 * k + 1];
      float py = (float)(ho - 1 + k / 3) + dy;
      float px = (float)(t - 1 + k % 3) + dx;
      float y0f = floorf(py), x0f = floorf(px);
      float wy1 = py - y0f, wy0 = 1.f - wy1;
      float wx1 = px - x0f, wx0 = 1.f - wx1;
      int y0 = (int)y0f, x0 = (int)x0f;
      bool vy0 = (unsigned)y0 < 64u, vy1 = (unsigned)(y0 + 1) < 64u;
      bool vx0 = (unsigned)x0 < 64u, vx1 = (unsigned)(x0 + 1) < 64u;
      float w00 = (vy0 && vx0) ? wy0 * wx0 : 0.f;
      float w01 = (vy0 && vx1) ? wy0 * wx1 : 0.f;
      float w10 = (vy1 && vx0) ? wy1 * wx0 : 0.f;
      float w11 = (vy1 && vx1) ? wy1 * wx1 : 0.f;
      int y0c = min(max(y0, 0), 63), y1c = min(max(y0 + 1, 0), 63);
      int xb2 = min(max(x0, 0), 62);
      unsigned off0 = (unsigned)(y0c * 64 + xb2);
      unsigned off1 = (unsigned)(y1c * 64 + xb2);
      unsigned pkw = off0 | (off1 << 12);
      if (x0 == 63) pkw |= (1u << 24);   // left value is loaded col+1
      if (x0 == -1) pkw |= (1u << 25);   // right value is loaded col
      int rec = (b * 9 + k) * HW + ho * 64 + t;
      w4out[rec] = make_float4(w00, w01, w10, w11);
      idxout[rec] = pkw;
    }
  }
}

// ---------------- fused deformable-im2col + MFMA GEMM + BN + SiLU ----------------
// 512 thr = 8 waves; wave wv: MFMA oc-tile wv AND stages records pos wv*8..wv*8+7.
// Gather: lanes span CHANNELS. One corner-pixel row (128ch bf16 = 256B) = one
// fully-coalesced dword load (4 cache lines), vs 64 scattered lines in r7.
// Per-record bilinear weights/indices are wave-uniform, stashed in LDS upfront.
__global__ __launch_bounds__(512, 4) void gemm_kernel(
    const unsigned short* __restrict__ xt, const unsigned short* __restrict__ wsW2,
    const float4* __restrict__ w4in, const unsigned int* __restrict__ idxin,
    const float* __restrict__ dbias, const float* __restrict__ gamma,
    const float* __restrict__ beta, const float* __restrict__ mean,
    const float* __restrict__ var, float* __restrict__ out) {
  int bid = blockIdx.x;
  int swz = (bid & 7) * 64 + (bid >> 3);           // XCD i <- batch i
  int b = swz >> 6, ho = swz & 63;
  int t = threadIdx.x;
  int lane = t & 63, wv = t >> 6;
  int col = lane & 15, g = lane >> 4;

  __shared__ unsigned short S[2][64 * SLD];        // 34816 B
  __shared__ float RW[576 * 4];                    //  9216 B  w4 per (k,pos)
  __shared__ unsigned RI[576];                     //  2304 B  idx per (k,pos)

  f32x4 acc[4];
#pragma unroll
  for (int j = 0; j < 4; ++j) acc[j] = (f32x4){0.f, 0.f, 0.f, 0.f};

  // prologue: cooperative stash of all 9x64 records for this (b,ho)
  for (int i = t; i < 576; i += 512) {
    int k = i >> 6, p = i & 63;
    size_t src = ((size_t)b * 9 + k) * HW + ho * 64 + p;
    float4 v = w4in[src];
    RW[i * 4 + 0] = v.x; RW[i * 4 + 1] = v.y;
    RW[i * 4 + 2] = v.z; RW[i * 4 + 3] = v.w;
    RI[i] = idxin[src];
  }

  const unsigned int* xtb32 = (const unsigned int*)(xt + (size_t)b * HW * 128);
  const unsigned short* wA = wsW2 + wv * (9 * 4 * 512) + lane * 8;

  // stage K-step kk into S[buf]: this wave's 8 records, lanes = 2ch each
  auto stage = [&](int kk, int buf) {
#pragma unroll
    for (int r = 0; r < 8; ++r) {
      int p = wv * 8 + r;
      int ridx = kk * 64 + p;
      unsigned pk = RI[ridx];
      float wx = RW[ridx * 4 + 0], wy = RW[ridx * 4 + 1];
      float wz = RW[ridx * 4 + 2], ww = RW[ridx * 4 + 3];
      int o0 = pk & 4095, o1 = (pk >> 12) & 4095;
      bool s0 = (pk >> 24) & 1, s1 = (pk >> 25) & 1;
      const unsigned int* r0 = xtb32 + o0 * 64;
      const unsigned int* r1 = xtb32 + o1 * 64;
      unsigned c00 = r0[lane], c01 = r0[lane + 64];
      unsigned c10 = r1[lane], c11 = r1[lane + 64];
      unsigned a0 = s0 ? c01 : c00, a1 = s1 ? c00 : c01;
      unsigned a2 = s0 ? c11 : c10, a3 = s1 ? c10 : c11;
      float lo = wx * b2f_lo(a0) + wy * b2f_lo(a1) + wz * b2f_lo(a2) + ww * b2f_lo(a3);
      float hi = wx * b2f_hi(a0) + wy * b2f_hi(a1) + wz * b2f_hi(a2) + ww * b2f_hi(a3);
      unsigned sm = ((unsigned)f2bf(lo)) | (((unsigned)f2bf(hi)) << 16);
      *(unsigned*)&S[buf][p * SLD + 2 * lane] = sm;
    }
  };

  __syncthreads();                                 // RW/RI visible
  stage(0, 0);
  __syncthreads();                                 // S[0] visible

  for (int k = 0; k < 9; ++k) {
    int cur = k & 1;
    if (k < 8) stage(k + 1, cur ^ 1);              // loads overlap MFMA below
    u16x8 af[4];
#pragma unroll
    for (int ks = 0; ks < 4; ++ks)
      af[ks] = *(const u16x8*)(wA + (k * 4 + ks) * 512);
#pragma unroll
    for (int pt = 0; pt < 4; ++pt)
#pragma unroll
      for (int ks = 0; ks < 4; ++ks) {
        bf16x8 bfr = *(const bf16x8*)&S[cur][(pt * 16 + col) * SLD + ks * 32 + g * 8];
        acc[pt] = __builtin_amdgcn_mfma_f32_16x16x32_bf16(
            __builtin_bit_cast(bf16x8, af[ks]), bfr, acc[pt], 0, 0, 0);
      }
    __syncthreads();
  }

  // epilogue: bias + BN + SiLU, write NCHW
  float* op = out + b * (Cout * HW) + ho * 64;
  int ocb = wv * 16 + g * 4;
#pragma unroll
  for (int r = 0; r < 4; ++r) {
    int oc = ocb + r;
    float sc = gamma[oc] * rsqrtf(var[oc] + 1e-5f);
    float bs = beta[oc] - mean[oc] * sc;
    float db = dbias[oc];
#pragma unroll
    for (int pt = 0; pt < 4; ++pt) {
      float v = (acc[pt][r] + db) * sc + bs;
      op[oc * HW + pt * 16 + col] = v / (1.f + __expf(-v));
    }
  }
}

extern "C" void kernel_launch(void* const* d_in, const int* in_sizes, int n_in,
                              void* d_out, int out_size, void* d_ws, size_t ws_size,
                              hipStream_t stream) {
  const float* x     = (const float*)d_in[0];
  const float* ow    = (const float*)d_in[1];
  const float* ob    = (const float*)d_in[2];
  const float* dw    = (const float*)d_in[3];
  const float* db    = (const float*)d_in[4];
  const float* gamma = (const float*)d_in[5];
  const float* beta  = (const float*)d_in[6];
  const float* mean  = (const float*)d_in[7];
  const float* var   = (const float*)d_in[8];

  char* wsc = (char*)d_ws;
  unsigned short* wsW2   = (unsigned short*)wsc;               // 294912 B
  unsigned short* wOffB2 = (unsigned short*)(wsc + 294912);    // 73728 B
  unsigned short* xt     = (unsigned short*)(wsc + 368640);    // 8388608 B
  float4* w4rec          = (float4*)(wsc + 8757248);           // 4718592 B
  unsigned int* idxrec   = (unsigned int*)(wsc + 13475840);    // 1179648 B

  prep_kernel<<<576, 256, 0, stream>>>(dw, ow, wsW2, wOffB2);
  trans_kernel<<<512, 256, 0, stream>>>(x, xt);
  offs_kernel<<<512, 256, 0, stream>>>(xt, wOffB2, ob, w4rec, idxrec);
  gemm_kernel<<<512, 512, 0, stream>>>(xt, wsW2, w4rec, idxrec, db, gamma, beta,
                                       mean, var, (float*)d_out);
}

// Round 9
// 56.686 us; speedup vs baseline: 2.4105x; 1.1702x over previous
//
#include <hip/hip_runtime.h>

typedef float f32x4 __attribute__((ext_vector_type(4)));
typedef __bf16 bf16x8 __attribute__((ext_vector_type(8)));
typedef unsigned short u16x8 __attribute__((ext_vector_type(8)));

static constexpr int B_ = 8, Cin = 128, Cout = 128, K2 = 9;
static constexpr int HW  = 64 * 64;      // 4096
static constexpr int CHW = Cin * HW;     // 524288
static constexpr int KC  = Cin * K2;     // 1152
static constexpr int SLD = 136;          // LDS row stride (u16), 272B

static __device__ __forceinline__ unsigned short f2bf(float f) {
  unsigned int u = __builtin_bit_cast(unsigned int, f);
  u = u + 0x7fffu + ((u >> 16) & 1u);
  return (unsigned short)(u >> 16);
}
static __device__ __forceinline__ float b2f_lo(unsigned int u) {
  return __builtin_bit_cast(float, u << 16);
}
static __device__ __forceinline__ float b2f_hi(unsigned int u) {
  return __builtin_bit_cast(float, u & 0xffff0000u);
}

// ---------------- kernel 1: prep (weight layouts) + transpose x -> NHWC bf16 ----
// wsW2:  [w(8)][k(9)][ks(4)][lane(64)][j(8)]  deform W, lane-contiguous A-frags
// wOffB2:[r(9)][ks(4)][m(2)][lane(64)][j(8)]  offset W (oc pad 18->32)
__global__ __launch_bounds__(256) void prep_trans_kernel(
    const float* __restrict__ x, const float* __restrict__ dw,
    const float* __restrict__ ow, unsigned short* __restrict__ wsW2,
    unsigned short* __restrict__ wOffB2, unsigned short* __restrict__ xt) {
  int bid = blockIdx.x;
  int t = threadIdx.x;

  // ---- transpose part: block (b,y) ----
  int swz = (bid & 7) * 64 + (bid >> 3);
  int b = swz >> 6, y = swz & 63;
  int lane = t & 63, cq = t >> 6;
  __shared__ unsigned short L[64 * SLD];
  const float* xb = x + b * CHW + y * 64;
#pragma unroll
  for (int i = 0; i < 32; ++i) {
    int c = i * 4 + cq;
    L[lane * SLD + c] = f2bf(xb[c * HW + lane]);
  }
  __syncthreads();
  int p = t >> 2, q = t & 3;
  unsigned short* op = xt + (size_t)b * HW * 128 + y * 64 * 128 + p * 128 + q * 32;
#pragma unroll
  for (int s = 0; s < 4; ++s)
    *(u16x8*)(op + s * 8) = *(const u16x8*)&L[p * SLD + q * 32 + s * 8];

  // ---- prep part (grid-strided over 512x256 = 131072 threads) ----
  for (int i = bid * 256 + t; i < 8 * 9 * 4 * 512; i += 512 * 256) {
    int j = i & 7, ln = (i >> 3) & 63, ks = (i >> 9) & 3, t2 = i >> 11;
    int k = t2 % 9, w = t2 / 9;
    int oc = w * 16 + (ln & 15);
    int c = ks * 32 + (ln >> 4) * 8 + j;
    wsW2[i] = f2bf(dw[(oc * Cin + c) * K2 + k]);
  }
  {
    int i = bid * 256 + t;
    if (i < 9 * 4 * 2 * 512) {
      int j = i & 7, ln = (i >> 3) & 63, m = (i >> 9) & 1, t3 = i >> 10;
      int ks = t3 & 3, r = t3 >> 2;
      int oc = m * 16 + (ln & 15);
      int c = ks * 32 + (ln >> 4) * 8 + j;
      wOffB2[i] = (oc < 18) ? f2bf(ow[(oc * Cin + c) * K2 + r]) : (unsigned short)0;
    }
  }
}

// ---------------- kernel 2: fused offset-conv + records + deform GEMM + BN/SiLU ----
// 512 thr = 8 waves, block = (b,ho).
// Phase A: offset conv via MFMA (waves 0-3 compute, all 8 stage; double-buffered SAB).
// Phase B: each wave computes bilinear records for its 8 positions x 9 taps -> LDS.
// Phase C: r8 gemm loop, loads issued before MFMA (T14), combine+write after.
__global__ __launch_bounds__(512, 4) void fused_kernel(
    const unsigned short* __restrict__ xt, const unsigned short* __restrict__ wsW2,
    const unsigned short* __restrict__ wOffB2, const float* __restrict__ ob,
    const float* __restrict__ dbias, const float* __restrict__ gamma,
    const float* __restrict__ beta, const float* __restrict__ mean,
    const float* __restrict__ var, float* __restrict__ out) {
  int bid = blockIdx.x;
  int swz = (bid & 7) * 64 + (bid >> 3);           // XCD i <- batch i
  int b = swz >> 6, ho = swz & 63;
  int t = threadIdx.x;
  int lane = t & 63, wv = t >> 6;
  int pos = lane;
  int col = lane & 15, g = lane >> 4;

  __shared__ unsigned short SAB[2][64 * SLD];      // 34816 B (A-stage & C-stage)
  __shared__ float T[64 * 20];                     //  5120 B offsets [pos][oc]
  __shared__ float RW4[576 * 4];                   //  9216 B bilinear weights
  __shared__ unsigned RI[576];                     //  2304 B packed indices

  const unsigned short* xtb = xt + (size_t)b * HW * 128;
  const unsigned int* xtb32 = (const unsigned int*)xtb;

  // ---------- phase A: offset conv ----------
  f32x4 accO[2];
  accO[0] = (f32x4){0.f, 0.f, 0.f, 0.f};
  accO[1] = (f32x4){0.f, 0.f, 0.f, 0.f};

  auto stageA = [&](int r, int buf) {              // 8 groups x 16 ch
    int ky = r / 3, kx = r % 3;
    int yv = ho + ky - 1, xc = pos + kx - 1;
    bool ok = ((unsigned)yv < 64u) && ((unsigned)xc < 64u);
    int yc = min(max(yv, 0), 63), xcc = min(max(xc, 0), 63);
    const unsigned short* qq = xtb + (yc * 64 + xcc) * 128 + wv * 16;
#pragma unroll
    for (int i = 0; i < 2; ++i) {
      u16x8 sm = *(const u16x8*)(qq + i * 8);
      if (!ok) sm = (u16x8){0, 0, 0, 0, 0, 0, 0, 0};
      *(u16x8*)&SAB[buf][pos * SLD + wv * 16 + i * 8] = sm;
    }
  };

  stageA(0, 0);
  __syncthreads();
  for (int r = 0; r < 9; ++r) {
    int cur = r & 1;
    if (r < 8) stageA(r + 1, cur ^ 1);
    if (wv < 4) {
#pragma unroll
      for (int ks = 0; ks < 4; ++ks) {
        bf16x8 bfr = *(const bf16x8*)&SAB[cur][(wv * 16 + col) * SLD + ks * 32 + g * 8];
        u16x8 af0 = *(const u16x8*)(wOffB2 + ((r * 4 + ks) * 2 + 0) * 512 + lane * 8);
        u16x8 af1 = *(const u16x8*)(wOffB2 + ((r * 4 + ks) * 2 + 1) * 512 + lane * 8);
        accO[0] = __builtin_amdgcn_mfma_f32_16x16x32_bf16(
            __builtin_bit_cast(bf16x8, af0), bfr, accO[0], 0, 0, 0);
        accO[1] = __builtin_amdgcn_mfma_f32_16x16x32_bf16(
            __builtin_bit_cast(bf16x8, af1), bfr, accO[1], 0, 0, 0);
      }
    }
    __syncthreads();
  }
  if (wv < 4) {                                    // D -> T[pos][oc] with bias
#pragma unroll
    for (int m = 0; m < 2; ++m)
#pragma unroll
      for (int rg = 0; rg < 4; ++rg) {
        int row = m * 16 + g * 4 + rg;
        if (row < 18) T[(wv * 16 + col) * 20 + row] = accO[m][rg] + ob[row];
      }
  }
  __syncthreads();

  // ---------- phase B: bilinear records (each wave: its 8 pos x 9 taps) ----------
#pragma unroll
  for (int it = 0; it < 2; ++it) {
    int idx = it * 64 + lane;
    if (idx < 72) {
      int k = idx >> 3, rr = idx & 7;
      int pp = wv * 8 + rr;
      float dy = T[pp * 20 + 2 * k], dx = T[pp * 20 + 2 * k + 1];
      float py = (float)(ho - 1 + k / 3) + dy;
      float px = (float)(pp - 1 + k % 3) + dx;
      float y0f = floorf(py), x0f = floorf(px);
      float wy1 = py - y0f, wy0 = 1.f - wy1;
      float wx1 = px - x0f, wx0 = 1.f - wx1;
      int y0 = (int)y0f, x0 = (int)x0f;
      bool vy0 = (unsigned)y0 < 64u, vy1 = (unsigned)(y0 + 1) < 64u;
      bool vx0 = (unsigned)x0 < 64u, vx1 = (unsigned)(x0 + 1) < 64u;
      float w00 = (vy0 && vx0) ? wy0 * wx0 : 0.f;
      float w01 = (vy0 && vx1) ? wy0 * wx1 : 0.f;
      float w10 = (vy1 && vx0) ? wy1 * wx0 : 0.f;
      float w11 = (vy1 && vx1) ? wy1 * wx1 : 0.f;
      int y0c = min(max(y0, 0), 63), y1c = min(max(y0 + 1, 0), 63);
      int xb2 = min(max(x0, 0), 62);
      unsigned pkw = (unsigned)(y0c * 64 + xb2) | ((unsigned)(y1c * 64 + xb2) << 12);
      if (x0 == 63) pkw |= (1u << 24);             // left value is loaded col+1
      if (x0 == -1) pkw |= (1u << 25);             // right value is loaded col
      int ridx = k * 64 + pp;
      RW4[ridx * 4 + 0] = w00; RW4[ridx * 4 + 1] = w01;
      RW4[ridx * 4 + 2] = w10; RW4[ridx * 4 + 3] = w11;
      RI[ridx] = pkw;
    }
  }
  __syncthreads();

  // ---------- phase C: deformable GEMM ----------
  f32x4 acc[4];
#pragma unroll
  for (int j = 0; j < 4; ++j) acc[j] = (f32x4){0.f, 0.f, 0.f, 0.f};
  const unsigned short* wA = wsW2 + wv * (9 * 4 * 512) + lane * 8;

  {                                                // prologue: stage k=0 full
#pragma unroll
    for (int r = 0; r < 8; ++r) {
      int pp = wv * 8 + r, ridx = pp;              // k = 0
      unsigned pk = RI[ridx];
      int o0 = pk & 4095, o1 = (pk >> 12) & 4095;
      bool s0 = (pk >> 24) & 1, s1 = (pk >> 25) & 1;
      const unsigned int* r0 = xtb32 + o0 * 64;
      const unsigned int* r1 = xtb32 + o1 * 64;
      unsigned c00 = r0[lane], c01 = r0[lane + 64];
      unsigned c10 = r1[lane], c11 = r1[lane + 64];
      unsigned a0 = s0 ? c01 : c00, a1 = s1 ? c00 : c01;
      unsigned a2 = s0 ? c11 : c10, a3 = s1 ? c10 : c11;
      float wx = RW4[ridx * 4], wy = RW4[ridx * 4 + 1];
      float wz = RW4[ridx * 4 + 2], ww = RW4[ridx * 4 + 3];
      float lo = wx * b2f_lo(a0) + wy * b2f_lo(a1) + wz * b2f_lo(a2) + ww * b2f_lo(a3);
      float hi = wx * b2f_hi(a0) + wy * b2f_hi(a1) + wz * b2f_hi(a2) + ww * b2f_hi(a3);
      *(unsigned*)&SAB[0][pp * SLD + 2 * lane] =
          ((unsigned)f2bf(lo)) | (((unsigned)f2bf(hi)) << 16);
    }
  }
  __syncthreads();

  for (int k = 0; k < 9; ++k) {
    int cur = k & 1;
    unsigned c00[8], c01[8], c10[8], c11[8];
    if (k < 8) {                                   // issue k+1 loads (T14: early)
#pragma unroll
      for (int r = 0; r < 8; ++r) {
        int ridx = (k + 1) * 64 + wv * 8 + r;
        unsigned pk = RI[ridx];
        int o0 = pk & 4095, o1 = (pk >> 12) & 4095;
        const unsigned int* r0 = xtb32 + o0 * 64;
        const unsigned int* r1 = xtb32 + o1 * 64;
        c00[r] = r0[lane]; c01[r] = r0[lane + 64];
        c10[r] = r1[lane]; c11[r] = r1[lane + 64];
      }
    }
    u16x8 af[4];
#pragma unroll
    for (int ks = 0; ks < 4; ++ks)
      af[ks] = *(const u16x8*)(wA + (k * 4 + ks) * 512);
#pragma unroll
    for (int pt = 0; pt < 4; ++pt)                 // 16 MFMA hide load latency
#pragma unroll
      for (int ks = 0; ks < 4; ++ks) {
        bf16x8 bfr = *(const bf16x8*)&SAB[cur][(pt * 16 + col) * SLD + ks * 32 + g * 8];
        acc[pt] = __builtin_amdgcn_mfma_f32_16x16x32_bf16(
            __builtin_bit_cast(bf16x8, af[ks]), bfr, acc[pt], 0, 0, 0);
      }
    if (k < 8) {                                   // combine + write (late)
#pragma unroll
      for (int r = 0; r < 8; ++r) {
        int ridx = (k + 1) * 64 + wv * 8 + r;
        unsigned pk = RI[ridx];
        bool s0 = (pk >> 24) & 1, s1 = (pk >> 25) & 1;
        float wx = RW4[ridx * 4], wy = RW4[ridx * 4 + 1];
        float wz = RW4[ridx * 4 + 2], ww = RW4[ridx * 4 + 3];
        unsigned a0 = s0 ? c01[r] : c00[r], a1 = s1 ? c00[r] : c01[r];
        unsigned a2 = s0 ? c11[r] : c10[r], a3 = s1 ? c10[r] : c11[r];
        float lo = wx * b2f_lo(a0) + wy * b2f_lo(a1) + wz * b2f_lo(a2) + ww * b2f_lo(a3);
        float hi = wx * b2f_hi(a0) + wy * b2f_hi(a1) + wz * b2f_hi(a2) + ww * b2f_hi(a3);
        *(unsigned*)&SAB[cur ^ 1][(wv * 8 + r) * SLD + 2 * lane] =
            ((unsigned)f2bf(lo)) | (((unsigned)f2bf(hi)) << 16);
      }
    }
    __syncthreads();
  }

  // epilogue: bias + BN + SiLU, write NCHW
  float* op = out + b * (Cout * HW) + ho * 64;
  int ocb = wv * 16 + g * 4;
#pragma unroll
  for (int r = 0; r < 4; ++r) {
    int oc = ocb + r;
    float sc = gamma[oc] * rsqrtf(var[oc] + 1e-5f);
    float bs = beta[oc] - mean[oc] * sc;
    float db = dbias[oc];
#pragma unroll
    for (int pt = 0; pt < 4; ++pt) {
      float v = (acc[pt][r] + db) * sc + bs;
      op[oc * HW + pt * 16 + col] = v / (1.f + __expf(-v));
    }
  }
}

extern "C" void kernel_launch(void* const* d_in, const int* in_sizes, int n_in,
                              void* d_out, int out_size, void* d_ws, size_t ws_size,
                              hipStream_t stream) {
  const float* x     = (const float*)d_in[0];
  const float* ow    = (const float*)d_in[1];
  const float* ob    = (const float*)d_in[2];
  const float* dw    = (const float*)d_in[3];
  const float* db    = (const float*)d_in[4];
  const float* gamma = (const float*)d_in[5];
  const float* beta  = (const float*)d_in[6];
  const float* mean  = (const float*)d_in[7];
  const float* var   = (const float*)d_in[8];

  char* wsc = (char*)d_ws;
  unsigned short* wsW2   = (unsigned short*)wsc;               // 294912 B
  unsigned short* wOffB2 = (unsigned short*)(wsc + 294912);    // 73728 B
  unsigned short* xt     = (unsigned short*)(wsc + 368640);    // 8388608 B

  prep_trans_kernel<<<512, 256, 0, stream>>>(x, dw, ow, wsW2, wOffB2, xt);
  fused_kernel<<<512, 512, 0, stream>>>(xt, wsW2, wOffB2, ob, db, gamma, beta,
                                        mean, var, (float*)d_out);
}